// Round 1
// baseline (3556.888 us; speedup 1.0000x reference)
//
#include <hip/hip_runtime.h>

// ---------------------------------------------------------------------------
// OT_Attn: unbalanced Sinkhorn on MI355X.
// Pipeline: zero -> prep(row-min shift, bf16, norms) -> MFMA cost GEMM (C f32,
// maxC) -> persistent cooperative Sinkhorn (K bf16 in LDS, 1 grid barrier/iter,
// atomic t-reduction) -> fused epilogue (flow.T + dist).
// ---------------------------------------------------------------------------

#define NROWS 4096
#define MCOLS 2048
#define NITER 100
#define NBLK  256   // sinkhorn grid: one block per 16 rows; <=256 CUs -> co-resident

using short8  = __attribute__((ext_vector_type(8))) short;
using floatx4 = __attribute__((ext_vector_type(4))) float;

__device__ __forceinline__ float bf2f(unsigned short u) {
  return __uint_as_float(((unsigned)u) << 16);
}
__device__ __forceinline__ unsigned short f2bf(float f) {  // RNE
  unsigned u = __float_as_uint(f);
  u += 0x7fffu + ((u >> 16) & 1u);
  return (unsigned short)(u >> 16);
}
__device__ __forceinline__ float powfi(float x, float fi) {
  return __expf(fi * __logf(x));
}

// ---------------------------------------------------------------------------
__global__ void zero_kernel(float* tbuf, unsigned* cnt, unsigned* flag,
                            unsigned* maxCbits, float* out) {
  const int g = blockIdx.x * 256 + threadIdx.x;
  if (g < 3 * 8 * 2048) tbuf[g] = 0.0f;          // 3 parity bufs x 8 replicas
  if (g == 0) { *cnt = 0u; *flag = 0u; *maxCbits = 0u; out[8388608] = 0.0f; }
}

// ---------------------------------------------------------------------------
// One block per row (4096 x-rows then 2048 y-rows): min-shift, bf16 round,
// squared norm OF THE ROUNDED VALUES (consistent with the bf16 GEMM).
__global__ __launch_bounds__(256) void prep_kernel(
    const float* __restrict__ x, const float* __restrict__ y,
    unsigned short* __restrict__ xb, unsigned short* __restrict__ yb,
    float* __restrict__ nx, float* __restrict__ ny) {
  const int row = blockIdx.x;
  const int tid = threadIdx.x;
  const float* src; unsigned short* dst; float* nd;
  if (row < NROWS) { src = x + (size_t)row * 1024; dst = xb + (size_t)row * 1024; nd = nx + row; }
  else { const int r = row - NROWS; src = y + (size_t)r * 1024; dst = yb + (size_t)r * 1024; nd = ny + r; }

  float4 v = ((const float4*)src)[tid];
  float mn = fminf(fminf(v.x, v.y), fminf(v.z, v.w));
  #pragma unroll
  for (int m = 1; m < 64; m <<= 1) mn = fminf(mn, __shfl_xor(mn, m));
  __shared__ float wred[4];
  const int w = tid >> 6, l = tid & 63;
  if (l == 0) wred[w] = mn;
  __syncthreads();
  mn = fminf(fminf(wred[0], wred[1]), fminf(wred[2], wred[3]));
  __syncthreads();   // wred reused below

  const unsigned short b0 = f2bf(v.x - mn), b1 = f2bf(v.y - mn);
  const unsigned short b2 = f2bf(v.z - mn), b3 = f2bf(v.w - mn);
  ushort4 ub; ub.x = b0; ub.y = b1; ub.z = b2; ub.w = b3;
  ((ushort4*)dst)[tid] = ub;
  const float f0 = bf2f(b0), f1 = bf2f(b1), f2 = bf2f(b2), f3 = bf2f(b3);
  float acc = f0 * f0 + f1 * f1 + f2 * f2 + f3 * f3;
  #pragma unroll
  for (int m = 1; m < 64; m <<= 1) acc += __shfl_xor(acc, m);
  if (l == 0) wred[w] = acc;
  __syncthreads();
  if (tid == 0) *nd = wred[0] + wred[1] + wred[2] + wred[3];
}

// ---------------------------------------------------------------------------
// C[i][j] = max(nx_i + ny_j - 2*dot(xb_i, yb_j), 0).  128x128 block tile,
// 4 waves as 2x2, each wave 64x64 = 4x4 MFMA 16x16x32 tiles, frags straight
// from global (L2-cached).  Also block-reduced atomicMax of C (uint trick).
__global__ __launch_bounds__(256) void cost_gemm_kernel(
    const unsigned short* __restrict__ xb, const unsigned short* __restrict__ yb,
    const float* __restrict__ nx, const float* __restrict__ ny,
    float* __restrict__ C, unsigned* __restrict__ maxCbits) {
  const int tid = threadIdx.x;
  const int w = tid >> 6, l = tid & 63;
  const int wr = w >> 1, wc = w & 1;
  const int i0 = blockIdx.y * 128 + wr * 64;
  const int j0 = blockIdx.x * 128 + wc * 64;
  const int m16 = l & 15, q = l >> 4;

  // A[m][k]: m=lane&15, k=quad*8+j ; B[k][n]: n=lane&15 (rows of Y = B^T trick)
  const unsigned short* ap = xb + (size_t)(i0 + m16) * 1024 + q * 8;
  const unsigned short* bp = yb + (size_t)(j0 + m16) * 1024 + q * 8;

  floatx4 acc[4][4];
  #pragma unroll
  for (int a = 0; a < 4; ++a)
    #pragma unroll
    for (int b = 0; b < 4; ++b) acc[a][b] = (floatx4){0.f, 0.f, 0.f, 0.f};

  for (int k0 = 0; k0 < 1024; k0 += 32) {
    short8 av[4], bv[4];
    #pragma unroll
    for (int t = 0; t < 4; ++t) av[t] = *(const short8*)(ap + (size_t)t * 16 * 1024 + k0);
    #pragma unroll
    for (int t = 0; t < 4; ++t) bv[t] = *(const short8*)(bp + (size_t)t * 16 * 1024 + k0);
    #pragma unroll
    for (int ti = 0; ti < 4; ++ti)
      #pragma unroll
      for (int tj = 0; tj < 4; ++tj)
        acc[ti][tj] = __builtin_amdgcn_mfma_f32_16x16x32_bf16(av[ti], bv[tj], acc[ti][tj], 0, 0, 0);
  }

  float mx = 0.f;
  #pragma unroll
  for (int ti = 0; ti < 4; ++ti) {
    #pragma unroll
    for (int tj = 0; tj < 4; ++tj) {
      const int i = i0 + ti * 16 + q * 4;       // C/D: row = quad*4+reg
      const int j = j0 + tj * 16 + m16;         //       col = lane&15
      const float nyj = ny[j];
      #pragma unroll
      for (int r = 0; r < 4; ++r) {
        float c = nx[i + r] + nyj - 2.0f * acc[ti][tj][r];
        c = fmaxf(c, 0.0f);
        C[(size_t)(i + r) * 2048 + j] = c;
        mx = fmaxf(mx, c);
      }
    }
  }
  __shared__ float mred[4];
  #pragma unroll
  for (int m = 1; m < 64; m <<= 1) mx = fmaxf(mx, __shfl_xor(mx, m));
  if (l == 0) mred[w] = mx;
  __syncthreads();
  if (tid == 0) {
    const float bm = fmaxf(fmaxf(mred[0], mred[1]), fmaxf(mred[2], mred[3]));
    atomicMax(maxCbits, __float_as_uint(bm));   // C >= 0 -> uint order == float order
  }
}

// ---------------------------------------------------------------------------
// Persistent Sinkhorn. 256 blocks x 256 threads, block owns rows i0..i0+15.
// K-slice (bf16) lives in LDS for all 100 iterations.  Per iteration:
//   pass1 (local): s_i = sum_j K_ij v_j ; u_i = (a/s_i)^fi
//   pass2: per-thread 8-col partials of t_j = sum_i K_ij u_i -> global atomics
//          into tbuf[it%3][bid%8][j]  (8 replicas cut same-address contention)
//   grid barrier (monotonic epoch), zero buffer (it+2)%3, v_j = (b/t_j)^fi
// Epilogue: flow.T[j][i] = u_i K_ij v_j (coalesced 64B stores), dist = sum C*flow.
__global__ __launch_bounds__(256) void sinkhorn_kernel(
    const float* __restrict__ C, const unsigned* __restrict__ maxCbits,
    float* __restrict__ tbuf, unsigned* cnt, unsigned* flag,
    float* __restrict__ out) {
  __shared__ __align__(16) unsigned short Ks[16 * 2048];  // 64 KB
  __shared__ __align__(16) float vs[2048];                // 8 KB
  __shared__ __align__(16) float uloc[16];
  __shared__ float dred[4];

  const int tid = threadIdx.x;
  const int bid = blockIdx.x;
  const int w = tid >> 6, l = tid & 63;
  const int i0 = bid * 16;

  const float fi = 0.8333333333333334f;   // 0.5/(0.5+0.1)
  const float av = 1.0f / 4096.0f;
  const float bv = 1.0f / 2048.0f;

  // ---- prologue: K tile -> LDS, v = 1/m
  {
    const float sc = -1.0f / (0.1f * __uint_as_float(*maxCbits));
    for (int il = 0; il < 16; ++il) {
      const float* cp = C + (size_t)(i0 + il) * 2048 + tid * 8;
      const float4 c0 = *(const float4*)cp;
      const float4 c1 = *(const float4*)(cp + 4);
      uint4 pk;
      pk.x = (unsigned)f2bf(__expf(c0.x * sc)) | ((unsigned)f2bf(__expf(c0.y * sc)) << 16);
      pk.y = (unsigned)f2bf(__expf(c0.z * sc)) | ((unsigned)f2bf(__expf(c0.w * sc)) << 16);
      pk.z = (unsigned)f2bf(__expf(c1.x * sc)) | ((unsigned)f2bf(__expf(c1.y * sc)) << 16);
      pk.w = (unsigned)f2bf(__expf(c1.z * sc)) | ((unsigned)f2bf(__expf(c1.w * sc)) << 16);
      *(uint4*)&Ks[il * 2048 + tid * 8] = pk;
    }
    const float4 vinit = make_float4(bv, bv, bv, bv);
    *(float4*)&vs[tid * 8] = vinit;
    *(float4*)&vs[tid * 8 + 4] = vinit;
  }
  __syncthreads();

  const int j0p = tid * 8;   // this thread's column chunk (pass2 / v / zero)

  for (int it = 0; it < NITER; ++it) {
    // ---- pass 1: wave w handles rows w*4..w*4+3, lanes stride col chunks
    float part[4] = {0.f, 0.f, 0.f, 0.f};
    const int r0 = w * 4;
    #pragma unroll
    for (int c = 0; c < 4; ++c) {
      const int j0 = c * 512 + l * 8;
      const float4 va = *(const float4*)&vs[j0];
      const float4 vb = *(const float4*)&vs[j0 + 4];
      #pragma unroll
      for (int rr = 0; rr < 4; ++rr) {
        const uint4 kb = *(const uint4*)&Ks[(r0 + rr) * 2048 + j0];
        part[rr] += bf2f((unsigned short)kb.x) * va.x + bf2f((unsigned short)(kb.x >> 16)) * va.y
                 +  bf2f((unsigned short)kb.y) * va.z + bf2f((unsigned short)(kb.y >> 16)) * va.w
                 +  bf2f((unsigned short)kb.z) * vb.x + bf2f((unsigned short)(kb.z >> 16)) * vb.y
                 +  bf2f((unsigned short)kb.w) * vb.z + bf2f((unsigned short)(kb.w >> 16)) * vb.w;
      }
    }
    #pragma unroll
    for (int m = 1; m < 64; m <<= 1) {
      part[0] += __shfl_xor(part[0], m);
      part[1] += __shfl_xor(part[1], m);
      part[2] += __shfl_xor(part[2], m);
      part[3] += __shfl_xor(part[3], m);
    }
    if (l == 0) {
      uloc[r0 + 0] = powfi(av / part[0], fi);
      uloc[r0 + 1] = powfi(av / part[1], fi);
      uloc[r0 + 2] = powfi(av / part[2], fi);
      uloc[r0 + 3] = powfi(av / part[3], fi);
    }
    __syncthreads();

    // ---- pass 2: per-thread 8 columns across all 16 rows
    float ur[16];
    *(float4*)&ur[0]  = *(const float4*)&uloc[0];
    *(float4*)&ur[4]  = *(const float4*)&uloc[4];
    *(float4*)&ur[8]  = *(const float4*)&uloc[8];
    *(float4*)&ur[12] = *(const float4*)&uloc[12];
    float tp[8] = {0.f, 0.f, 0.f, 0.f, 0.f, 0.f, 0.f, 0.f};
    #pragma unroll
    for (int il = 0; il < 16; ++il) {
      const uint4 kb = *(const uint4*)&Ks[il * 2048 + j0p];
      const float uv = ur[il];
      tp[0] += bf2f((unsigned short)kb.x) * uv;
      tp[1] += bf2f((unsigned short)(kb.x >> 16)) * uv;
      tp[2] += bf2f((unsigned short)kb.y) * uv;
      tp[3] += bf2f((unsigned short)(kb.y >> 16)) * uv;
      tp[4] += bf2f((unsigned short)kb.z) * uv;
      tp[5] += bf2f((unsigned short)(kb.z >> 16)) * uv;
      tp[6] += bf2f((unsigned short)kb.w) * uv;
      tp[7] += bf2f((unsigned short)(kb.w >> 16)) * uv;
    }
    {
      float* tb = tbuf + (it % 3) * 16384 + (bid & 7) * 2048 + j0p;
      #pragma unroll
      for (int k = 0; k < 8; ++k) unsafeAtomicAdd(&tb[k], tp[k]);
    }

    // ---- grid barrier (monotonic epoch; fences give cross-XCD visibility)
    __syncthreads();
    if (tid == 0) {
      __threadfence();
      const unsigned epoch = (unsigned)(it + 1);
      const unsigned prev = atomicAdd(cnt, 1u);
      if (prev == epoch * (unsigned)NBLK - 1u) {
        __hip_atomic_store(flag, epoch, __ATOMIC_RELEASE, __HIP_MEMORY_SCOPE_AGENT);
      } else {
        while (__hip_atomic_load(flag, __ATOMIC_ACQUIRE, __HIP_MEMORY_SCOPE_AGENT) < epoch) {
          __builtin_amdgcn_s_sleep(2);
        }
      }
      __threadfence();
    }
    __syncthreads();

    // ---- zero buffer for iteration it+2 (race-free: consumed only after
    //      barrier it+1; its last readers finished before barrier it)
    {
      const int g = bid * 256 + tid;
      if (g < 16384) tbuf[((it + 2) % 3) * 16384 + g] = 0.0f;
    }

    // ---- v update (sum 8 replicas), store to LDS
    {
      const float* tbl = tbuf + (it % 3) * 16384;
      float tj[8] = {0.f, 0.f, 0.f, 0.f, 0.f, 0.f, 0.f, 0.f};
      #pragma unroll
      for (int rep = 0; rep < 8; ++rep) {
        const float4 t0 = *(const float4*)&tbl[rep * 2048 + j0p];
        const float4 t1 = *(const float4*)&tbl[rep * 2048 + j0p + 4];
        tj[0] += t0.x; tj[1] += t0.y; tj[2] += t0.z; tj[3] += t0.w;
        tj[4] += t1.x; tj[5] += t1.y; tj[6] += t1.z; tj[7] += t1.w;
      }
      float vv[8];
      #pragma unroll
      for (int k = 0; k < 8; ++k) vv[k] = powfi(bv / tj[k], fi);
      *(float4*)&vs[j0p]     = make_float4(vv[0], vv[1], vv[2], vv[3]);
      *(float4*)&vs[j0p + 4] = make_float4(vv[4], vv[5], vv[6], vv[7]);
    }
    __syncthreads();
  }

  // ---- epilogue: flow.T[j][i0..i0+15] (64B contiguous stores) + dist
  float ur[16];
  *(float4*)&ur[0]  = *(const float4*)&uloc[0];
  *(float4*)&ur[4]  = *(const float4*)&uloc[4];
  *(float4*)&ur[8]  = *(const float4*)&uloc[8];
  *(float4*)&ur[12] = *(const float4*)&uloc[12];
  float distp = 0.f;
  for (int sub = 0; sub < 8; ++sub) {
    const int j = w * 512 + sub * 64 + l;
    const float vj = vs[j];
    float o[16];
    #pragma unroll
    for (int il = 0; il < 16; ++il) {
      const float kf = bf2f(Ks[il * 2048 + j]);
      const float fl = ur[il] * kf * vj;
      o[il] = fl;
      distp += C[(size_t)(i0 + il) * 2048 + j] * fl;
    }
    float* op = out + (size_t)j * 4096 + i0;
    *(float4*)(op)      = make_float4(o[0],  o[1],  o[2],  o[3]);
    *(float4*)(op + 4)  = make_float4(o[4],  o[5],  o[6],  o[7]);
    *(float4*)(op + 8)  = make_float4(o[8],  o[9],  o[10], o[11]);
    *(float4*)(op + 12) = make_float4(o[12], o[13], o[14], o[15]);
  }
  #pragma unroll
  for (int m = 1; m < 64; m <<= 1) distp += __shfl_xor(distp, m);
  if (l == 0) dred[w] = distp;
  __syncthreads();
  if (tid == 0) unsafeAtomicAdd(out + (size_t)8388608, dred[0] + dred[1] + dred[2] + dred[3]);
}

// ---------------------------------------------------------------------------
extern "C" void kernel_launch(void* const* d_in, const int* in_sizes, int n_in,
                              void* d_out, int out_size, void* d_ws, size_t ws_size,
                              hipStream_t stream) {
  (void)in_sizes; (void)n_in; (void)out_size; (void)ws_size;
  const float* x = (const float*)d_in[0];
  const float* y = (const float*)d_in[1];
  float* out = (float*)d_out;
  char* ws = (char*)d_ws;

  // workspace layout (bytes)
  float*          Cmat = (float*)(ws + 0);                 // 4096*2048 f32 = 32 MB
  unsigned short* xb   = (unsigned short*)(ws + 33554432); // 4096*1024 bf16 = 8 MB
  unsigned short* yb   = (unsigned short*)(ws + 41943040); // 2048*1024 bf16 = 4 MB
  float*          nx   = (float*)(ws + 46137344);          // 4096 f32
  float*          ny   = (float*)(ws + 46153728);          // 2048 f32
  unsigned*       maxC = (unsigned*)(ws + 46161920);
  unsigned*       cnt  = (unsigned*)(ws + 46162048);
  unsigned*       flag = (unsigned*)(ws + 46162176);
  float*          tbuf = (float*)(ws + 46162432);          // 3*8*2048 f32 = 192 KB

  hipLaunchKernelGGL(zero_kernel, dim3(192), dim3(256), 0, stream, tbuf, cnt, flag, maxC, out);
  hipLaunchKernelGGL(prep_kernel, dim3(6144), dim3(256), 0, stream, x, y, xb, yb, nx, ny);
  hipLaunchKernelGGL(cost_gemm_kernel, dim3(16, 32), dim3(256), 0, stream, xb, yb, nx, ny, Cmat, maxC);
  hipLaunchKernelGGL(sinkhorn_kernel, dim3(NBLK), dim3(256), 0, stream, Cmat, maxC, tbuf, cnt, flag, out);
}

// Round 2
// 2930.379 us; speedup vs baseline: 1.2138x; 1.2138x over previous
//
#include <hip/hip_runtime.h>

// ---------------------------------------------------------------------------
// OT_Attn: unbalanced Sinkhorn on MI355X.
// Pipeline: zero -> prep(row-min shift, bf16, norms) -> MFMA cost GEMM (C f32,
// maxC) -> persistent cooperative Sinkhorn (K bf16 in LDS, store/reduce/bcast
// t-reduction with 2 grid barriers per iter) -> fused epilogue (flow.T + dist).
// R2: replaced 524K/iter fire-and-forget f32 atomics (32B-granule wall, 15 G/s
// = whole 3.4 ms) with coalesced partial stores + tree reduce + broadcast.
// ---------------------------------------------------------------------------

#define NROWS 4096
#define MCOLS 2048
#define NITER 100
#define NBLK  256   // sinkhorn grid: one block per 16 rows; co-resident

using short8  = __attribute__((ext_vector_type(8))) short;
using floatx4 = __attribute__((ext_vector_type(4))) float;

__device__ __forceinline__ float bf2f(unsigned short u) {
  return __uint_as_float(((unsigned)u) << 16);
}
__device__ __forceinline__ unsigned short f2bf(float f) {  // RNE
  unsigned u = __float_as_uint(f);
  u += 0x7fffu + ((u >> 16) & 1u);
  return (unsigned short)(u >> 16);
}
__device__ __forceinline__ float powfi(float x, float fi) {
  return __expf(fi * __logf(x));
}

// Two-level grid barrier, monotonic epochs. Called by tid==0 only, wrapped in
// __syncthreads() by the caller. grp: 16 counters on own 128B lines; 16 blocks
// (bid&15) per group; last group-arriver bumps root; 16th root-arriver sets
// flag=ep. Relaxed atomics + explicit threadfences (wbl2 before / inv after).
__device__ __forceinline__ void grid_barrier(unsigned ep, unsigned* grp,
                                             unsigned* root, unsigned* flag,
                                             int bid) {
  __threadfence();   // flush my partial stores (L2 wbl2) + drain
  const unsigned prev = __hip_atomic_fetch_add(&grp[(bid & 15) * 32], 1u,
                          __ATOMIC_RELAXED, __HIP_MEMORY_SCOPE_AGENT);
  if (prev == ep * 16u - 1u) {
    const unsigned p2 = __hip_atomic_fetch_add(root, 1u,
                          __ATOMIC_RELAXED, __HIP_MEMORY_SCOPE_AGENT);
    if (p2 == ep * 16u - 1u)
      __hip_atomic_store(flag, ep, __ATOMIC_RELAXED, __HIP_MEMORY_SCOPE_AGENT);
  }
  while (__hip_atomic_load(flag, __ATOMIC_RELAXED, __HIP_MEMORY_SCOPE_AGENT) < ep)
    __builtin_amdgcn_s_sleep(1);
  __threadfence();   // invalidate L1/L2 so we see others' partials
}

// ---------------------------------------------------------------------------
__global__ void zero_kernel(unsigned* bar, unsigned* maxCbits, float* out) {
  const int g = blockIdx.x * 256 + threadIdx.x;
  if (g < 640) bar[g] = 0u;   // grp[16*32] + root + flag (128B-padded)
  if (g == 0) { *maxCbits = 0u; out[8388608] = 0.0f; }
}

// ---------------------------------------------------------------------------
// One block per row (4096 x-rows then 2048 y-rows): min-shift, bf16 round,
// squared norm OF THE ROUNDED VALUES (consistent with the bf16 GEMM).
__global__ __launch_bounds__(256) void prep_kernel(
    const float* __restrict__ x, const float* __restrict__ y,
    unsigned short* __restrict__ xb, unsigned short* __restrict__ yb,
    float* __restrict__ nx, float* __restrict__ ny) {
  const int row = blockIdx.x;
  const int tid = threadIdx.x;
  const float* src; unsigned short* dst; float* nd;
  if (row < NROWS) { src = x + (size_t)row * 1024; dst = xb + (size_t)row * 1024; nd = nx + row; }
  else { const int r = row - NROWS; src = y + (size_t)r * 1024; dst = yb + (size_t)r * 1024; nd = ny + r; }

  float4 v = ((const float4*)src)[tid];
  float mn = fminf(fminf(v.x, v.y), fminf(v.z, v.w));
  #pragma unroll
  for (int m = 1; m < 64; m <<= 1) mn = fminf(mn, __shfl_xor(mn, m));
  __shared__ float wred[4];
  const int w = tid >> 6, l = tid & 63;
  if (l == 0) wred[w] = mn;
  __syncthreads();
  mn = fminf(fminf(wred[0], wred[1]), fminf(wred[2], wred[3]));
  __syncthreads();   // wred reused below

  const unsigned short b0 = f2bf(v.x - mn), b1 = f2bf(v.y - mn);
  const unsigned short b2 = f2bf(v.z - mn), b3 = f2bf(v.w - mn);
  ushort4 ub; ub.x = b0; ub.y = b1; ub.z = b2; ub.w = b3;
  ((ushort4*)dst)[tid] = ub;
  const float f0 = bf2f(b0), f1 = bf2f(b1), f2 = bf2f(b2), f3 = bf2f(b3);
  float acc = f0 * f0 + f1 * f1 + f2 * f2 + f3 * f3;
  #pragma unroll
  for (int m = 1; m < 64; m <<= 1) acc += __shfl_xor(acc, m);
  if (l == 0) wred[w] = acc;
  __syncthreads();
  if (tid == 0) *nd = wred[0] + wred[1] + wred[2] + wred[3];
}

// ---------------------------------------------------------------------------
// C[i][j] = max(nx_i + ny_j - 2*dot(xb_i, yb_j), 0).  128x128 block tile,
// 4 waves as 2x2, each wave 64x64 = 4x4 MFMA 16x16x32 tiles, frags straight
// from global (L2-cached).  Also block-reduced atomicMax of C (uint trick).
__global__ __launch_bounds__(256) void cost_gemm_kernel(
    const unsigned short* __restrict__ xb, const unsigned short* __restrict__ yb,
    const float* __restrict__ nx, const float* __restrict__ ny,
    float* __restrict__ C, unsigned* __restrict__ maxCbits) {
  const int tid = threadIdx.x;
  const int w = tid >> 6, l = tid & 63;
  const int wr = w >> 1, wc = w & 1;
  const int i0 = blockIdx.y * 128 + wr * 64;
  const int j0 = blockIdx.x * 128 + wc * 64;
  const int m16 = l & 15, q = l >> 4;

  const unsigned short* ap = xb + (size_t)(i0 + m16) * 1024 + q * 8;
  const unsigned short* bp = yb + (size_t)(j0 + m16) * 1024 + q * 8;

  floatx4 acc[4][4];
  #pragma unroll
  for (int a = 0; a < 4; ++a)
    #pragma unroll
    for (int b = 0; b < 4; ++b) acc[a][b] = (floatx4){0.f, 0.f, 0.f, 0.f};

  for (int k0 = 0; k0 < 1024; k0 += 32) {
    short8 av[4], bv[4];
    #pragma unroll
    for (int t = 0; t < 4; ++t) av[t] = *(const short8*)(ap + (size_t)t * 16 * 1024 + k0);
    #pragma unroll
    for (int t = 0; t < 4; ++t) bv[t] = *(const short8*)(bp + (size_t)t * 16 * 1024 + k0);
    #pragma unroll
    for (int ti = 0; ti < 4; ++ti)
      #pragma unroll
      for (int tj = 0; tj < 4; ++tj)
        acc[ti][tj] = __builtin_amdgcn_mfma_f32_16x16x32_bf16(av[ti], bv[tj], acc[ti][tj], 0, 0, 0);
  }

  float mx = 0.f;
  #pragma unroll
  for (int ti = 0; ti < 4; ++ti) {
    #pragma unroll
    for (int tj = 0; tj < 4; ++tj) {
      const int i = i0 + ti * 16 + q * 4;       // C/D: row = quad*4+reg
      const int j = j0 + tj * 16 + m16;         //       col = lane&15
      const float nyj = ny[j];
      #pragma unroll
      for (int r = 0; r < 4; ++r) {
        float c = nx[i + r] + nyj - 2.0f * acc[ti][tj][r];
        c = fmaxf(c, 0.0f);
        C[(size_t)(i + r) * 2048 + j] = c;
        mx = fmaxf(mx, c);
      }
    }
  }
  __shared__ float mred[4];
  #pragma unroll
  for (int m = 1; m < 64; m <<= 1) mx = fmaxf(mx, __shfl_xor(mx, m));
  if (l == 0) mred[w] = mx;
  __syncthreads();
  if (tid == 0) {
    const float bm = fmaxf(fmaxf(mred[0], mred[1]), fmaxf(mred[2], mred[3]));
    atomicMax(maxCbits, __float_as_uint(bm));   // C >= 0 -> uint order == float order
  }
}

// ---------------------------------------------------------------------------
// Persistent Sinkhorn. 256 blocks x 256 threads, block owns rows i0..i0+15.
// K-slice (bf16) lives in LDS for all 100 iterations.  Per iteration:
//   pass1 (local): s_i = sum_j K_ij v_j ; u_i = (a/s_i)^fi
//   pass2: per-thread 8-col partials of t_j -> P[bid][j] (coalesced stores)
//   barrier1 ; stage B: block b reduces cols [8b,8b+8) over 256 partials,
//   v_j = (b/t_j)^fi -> vglob ; barrier2 ; broadcast vglob -> LDS vs.
// Epilogue: flow.T[j][i] = u_i K_ij v_j (coalesced 64B stores), dist = sum C*flow.
__global__ __launch_bounds__(256) void sinkhorn_kernel(
    const float* __restrict__ C, const unsigned* __restrict__ maxCbits,
    float* __restrict__ P, float* __restrict__ vglob,
    unsigned* grp, unsigned* root, unsigned* flag,
    float* __restrict__ out) {
  __shared__ __align__(16) unsigned short Ks[16 * 2048];  // 64 KB
  __shared__ __align__(16) float vs[2048];                // 8 KB
  __shared__ __align__(16) float uloc[16];
  __shared__ __align__(16) float bred[4][8];
  __shared__ float dred[4];

  const int tid = threadIdx.x;
  const int bid = blockIdx.x;
  const int w = tid >> 6, l = tid & 63;
  const int i0 = bid * 16;

  const float fi = 0.8333333333333334f;   // 0.5/(0.5+0.1)
  const float av = 1.0f / 4096.0f;
  const float bv = 1.0f / 2048.0f;

  // ---- prologue: K tile -> LDS, v = 1/m
  {
    const float sc = -1.0f / (0.1f * __uint_as_float(*maxCbits));
    for (int il = 0; il < 16; ++il) {
      const float* cp = C + (size_t)(i0 + il) * 2048 + tid * 8;
      const float4 c0 = *(const float4*)cp;
      const float4 c1 = *(const float4*)(cp + 4);
      uint4 pk;
      pk.x = (unsigned)f2bf(__expf(c0.x * sc)) | ((unsigned)f2bf(__expf(c0.y * sc)) << 16);
      pk.y = (unsigned)f2bf(__expf(c0.z * sc)) | ((unsigned)f2bf(__expf(c0.w * sc)) << 16);
      pk.z = (unsigned)f2bf(__expf(c1.x * sc)) | ((unsigned)f2bf(__expf(c1.y * sc)) << 16);
      pk.w = (unsigned)f2bf(__expf(c1.z * sc)) | ((unsigned)f2bf(__expf(c1.w * sc)) << 16);
      *(uint4*)&Ks[il * 2048 + tid * 8] = pk;
    }
    const float4 vinit = make_float4(bv, bv, bv, bv);
    *(float4*)&vs[tid * 8] = vinit;
    *(float4*)&vs[tid * 8 + 4] = vinit;
  }
  __syncthreads();

  const int j0p = tid * 8;   // this thread's column chunk (pass2 / bcast)
  const int jb  = bid * 8;   // this block's stage-B column chunk

  for (int it = 0; it < NITER; ++it) {
    // ---- pass 1: wave w handles rows w*4..w*4+3, lanes stride col chunks
    float part[4] = {0.f, 0.f, 0.f, 0.f};
    const int r0 = w * 4;
    #pragma unroll
    for (int c = 0; c < 4; ++c) {
      const int j0 = c * 512 + l * 8;
      const float4 va = *(const float4*)&vs[j0];
      const float4 vb = *(const float4*)&vs[j0 + 4];
      #pragma unroll
      for (int rr = 0; rr < 4; ++rr) {
        const uint4 kb = *(const uint4*)&Ks[(r0 + rr) * 2048 + j0];
        part[rr] += bf2f((unsigned short)kb.x) * va.x + bf2f((unsigned short)(kb.x >> 16)) * va.y
                 +  bf2f((unsigned short)kb.y) * va.z + bf2f((unsigned short)(kb.y >> 16)) * va.w
                 +  bf2f((unsigned short)kb.z) * vb.x + bf2f((unsigned short)(kb.z >> 16)) * vb.y
                 +  bf2f((unsigned short)kb.w) * vb.z + bf2f((unsigned short)(kb.w >> 16)) * vb.w;
      }
    }
    #pragma unroll
    for (int m = 1; m < 64; m <<= 1) {
      part[0] += __shfl_xor(part[0], m);
      part[1] += __shfl_xor(part[1], m);
      part[2] += __shfl_xor(part[2], m);
      part[3] += __shfl_xor(part[3], m);
    }
    if (l == 0) {
      uloc[r0 + 0] = powfi(av / part[0], fi);
      uloc[r0 + 1] = powfi(av / part[1], fi);
      uloc[r0 + 2] = powfi(av / part[2], fi);
      uloc[r0 + 3] = powfi(av / part[3], fi);
    }
    __syncthreads();

    // ---- pass 2: per-thread 8 columns across all 16 rows -> P[bid][j]
    float ur[16];
    *(float4*)&ur[0]  = *(const float4*)&uloc[0];
    *(float4*)&ur[4]  = *(const float4*)&uloc[4];
    *(float4*)&ur[8]  = *(const float4*)&uloc[8];
    *(float4*)&ur[12] = *(const float4*)&uloc[12];
    float tp[8] = {0.f, 0.f, 0.f, 0.f, 0.f, 0.f, 0.f, 0.f};
    #pragma unroll
    for (int il = 0; il < 16; ++il) {
      const uint4 kb = *(const uint4*)&Ks[il * 2048 + j0p];
      const float uv = ur[il];
      tp[0] += bf2f((unsigned short)kb.x) * uv;
      tp[1] += bf2f((unsigned short)(kb.x >> 16)) * uv;
      tp[2] += bf2f((unsigned short)kb.y) * uv;
      tp[3] += bf2f((unsigned short)(kb.y >> 16)) * uv;
      tp[4] += bf2f((unsigned short)kb.z) * uv;
      tp[5] += bf2f((unsigned short)(kb.z >> 16)) * uv;
      tp[6] += bf2f((unsigned short)kb.w) * uv;
      tp[7] += bf2f((unsigned short)(kb.w >> 16)) * uv;
    }
    {
      float* pb = P + (size_t)bid * 2048 + j0p;
      *(float4*)(pb)     = make_float4(tp[0], tp[1], tp[2], tp[3]);
      *(float4*)(pb + 4) = make_float4(tp[4], tp[5], tp[6], tp[7]);
    }

    // ---- barrier 1 (partials visible everywhere after this)
    __syncthreads();
    if (tid == 0) grid_barrier(2u * it + 1u, grp, root, flag, bid);
    __syncthreads();

    // ---- stage B: reduce this block's 8 columns over 256 partial rows
    {
      const float* pr = P + (size_t)tid * 2048 + jb;
      const float4 p0 = *(const float4*)(pr);
      const float4 p1 = *(const float4*)(pr + 4);
      float r8[8] = {p0.x, p0.y, p0.z, p0.w, p1.x, p1.y, p1.z, p1.w};
      #pragma unroll
      for (int m = 1; m < 64; m <<= 1) {
        #pragma unroll
        for (int k = 0; k < 8; ++k) r8[k] += __shfl_xor(r8[k], m);
      }
      if (l == 0) {
        *(float4*)&bred[w][0] = make_float4(r8[0], r8[1], r8[2], r8[3]);
        *(float4*)&bred[w][4] = make_float4(r8[4], r8[5], r8[6], r8[7]);
      }
      __syncthreads();
      if (tid < 8) {
        const float tj = bred[0][tid] + bred[1][tid] + bred[2][tid] + bred[3][tid];
        vglob[jb + tid] = powfi(bv / tj, fi);
      }
    }

    // ---- barrier 2 (v visible everywhere after this)
    __syncthreads();
    if (tid == 0) grid_barrier(2u * it + 2u, grp, root, flag, bid);
    __syncthreads();

    // ---- broadcast: vglob -> LDS vs
    *(float4*)&vs[j0p]     = *(const float4*)&vglob[j0p];
    *(float4*)&vs[j0p + 4] = *(const float4*)&vglob[j0p + 4];
    __syncthreads();
  }

  // ---- epilogue: flow.T[j][i0..i0+15] (64B contiguous stores) + dist
  float ur[16];
  *(float4*)&ur[0]  = *(const float4*)&uloc[0];
  *(float4*)&ur[4]  = *(const float4*)&uloc[4];
  *(float4*)&ur[8]  = *(const float4*)&uloc[8];
  *(float4*)&ur[12] = *(const float4*)&uloc[12];
  float distp = 0.f;
  for (int sub = 0; sub < 8; ++sub) {
    const int j = w * 512 + sub * 64 + l;
    const float vj = vs[j];
    float o[16];
    #pragma unroll
    for (int il = 0; il < 16; ++il) {
      const float kf = bf2f(Ks[il * 2048 + j]);
      const float fl = ur[il] * kf * vj;
      o[il] = fl;
      distp += C[(size_t)(i0 + il) * 2048 + j] * fl;
    }
    float* op = out + (size_t)j * 4096 + i0;
    *(float4*)(op)      = make_float4(o[0],  o[1],  o[2],  o[3]);
    *(float4*)(op + 4)  = make_float4(o[4],  o[5],  o[6],  o[7]);
    *(float4*)(op + 8)  = make_float4(o[8],  o[9],  o[10], o[11]);
    *(float4*)(op + 12) = make_float4(o[12], o[13], o[14], o[15]);
  }
  #pragma unroll
  for (int m = 1; m < 64; m <<= 1) distp += __shfl_xor(distp, m);
  if (l == 0) dred[w] = distp;
  __syncthreads();
  if (tid == 0) unsafeAtomicAdd(out + (size_t)8388608, dred[0] + dred[1] + dred[2] + dred[3]);
}

// ---------------------------------------------------------------------------
extern "C" void kernel_launch(void* const* d_in, const int* in_sizes, int n_in,
                              void* d_out, int out_size, void* d_ws, size_t ws_size,
                              hipStream_t stream) {
  (void)in_sizes; (void)n_in; (void)out_size; (void)ws_size;
  const float* x = (const float*)d_in[0];
  const float* y = (const float*)d_in[1];
  float* out = (float*)d_out;
  char* ws = (char*)d_ws;

  // workspace layout (bytes)
  float*          Cmat  = (float*)(ws + 0);                 // 4096*2048 f32 = 32 MB
  unsigned short* xb    = (unsigned short*)(ws + 33554432); // 4096*1024 bf16 = 8 MB
  unsigned short* yb    = (unsigned short*)(ws + 41943040); // 2048*1024 bf16 = 4 MB
  float*          nx    = (float*)(ws + 46137344);          // 4096 f32
  float*          ny    = (float*)(ws + 46153728);          // 2048 f32
  unsigned*       maxC  = (unsigned*)(ws + 46161920);
  unsigned*       bar   = (unsigned*)(ws + 46162048);       // grp[16*32]+root+flag
  unsigned*       grp   = bar;
  unsigned*       root  = (unsigned*)(ws + 46164096);
  unsigned*       flag  = (unsigned*)(ws + 46164224);
  // P and vglob alias xb's region: xb is dead after cost_gemm, and the
  // sinkhorn kernel only writes them after xb's last read.
  float*          P     = (float*)(ws + 33554432);          // 256*2048 f32 = 2 MB
  float*          vglob = (float*)(ws + 33554432 + 2097152);// 2048 f32

  hipLaunchKernelGGL(zero_kernel, dim3(4), dim3(256), 0, stream, bar, maxC, out);
  hipLaunchKernelGGL(prep_kernel, dim3(6144), dim3(256), 0, stream, x, y, xb, yb, nx, ny);
  hipLaunchKernelGGL(cost_gemm_kernel, dim3(16, 32), dim3(256), 0, stream, xb, yb, nx, ny, Cmat, maxC);
  hipLaunchKernelGGL(sinkhorn_kernel, dim3(NBLK), dim3(256), 0, stream,
                     Cmat, maxC, P, vglob, grp, root, flag, out);
}

// Round 3
// 1289.989 us; speedup vs baseline: 2.7573x; 2.2716x over previous
//
#include <hip/hip_runtime.h>

// ---------------------------------------------------------------------------
// OT_Attn: unbalanced Sinkhorn on MI355X.
// R3: ZERO grid barriers, zero cache-maintenance ops. R2's 28 us/iter was
// 1024 full-L2 wbl2/inv walks per iter (agent __threadfence in the barrier).
// Now: pure dataflow. Every cross-block value is an 8-byte (f32 value, u32
// iteration-tag) pair moved with relaxed AGENT atomics (sc0 sc1 -> straight
// to IF, no L2 pollution/staleness possible). Consumers poll the tag in the
// data. Each block owns 16 rows (Ks in LDS) AND 8 columns (KsT in LDS), so
// t_j is computed fully locally -- no partial-reduce stage.
// Flow control is structural: u^(k+2) needs all v^(k+1), which needed all
// u^(k+1) consumed -> single-buffer tags are race-free. Tags 1..100 never
// collide with 0xAA poison (ws re-poisoned before every launch).
// ---------------------------------------------------------------------------

#define NROWS 4096
#define MCOLS 2048
#define NITER 100
#define NBLK  256   // 1 block/CU (LDS-bound), grid == CU count -> co-resident

using short8  = __attribute__((ext_vector_type(8))) short;
using floatx4 = __attribute__((ext_vector_type(4))) float;

__device__ __forceinline__ float bf2f(unsigned short u) {
  return __uint_as_float(((unsigned)u) << 16);
}
__device__ __forceinline__ unsigned short f2bf(float f) {  // RNE
  unsigned u = __float_as_uint(f);
  u += 0x7fffu + ((u >> 16) & 1u);
  return (unsigned short)(u >> 16);
}
__device__ __forceinline__ float powfi(float x, float fi) {
  return __expf(fi * __logf(x));
}
__device__ __forceinline__ unsigned long long packvt(float v, unsigned tag) {
  return ((unsigned long long)tag << 32) | (unsigned long long)__float_as_uint(v);
}

// ---------------------------------------------------------------------------
__global__ void zero_kernel(unsigned* maxCbits, float* out) {
  if (threadIdx.x == 0) { *maxCbits = 0u; out[8388608] = 0.0f; }
}

// ---------------------------------------------------------------------------
// One block per row (4096 x-rows then 2048 y-rows): min-shift, bf16 round,
// squared norm OF THE ROUNDED VALUES (consistent with the bf16 GEMM).
__global__ __launch_bounds__(256) void prep_kernel(
    const float* __restrict__ x, const float* __restrict__ y,
    unsigned short* __restrict__ xb, unsigned short* __restrict__ yb,
    float* __restrict__ nx, float* __restrict__ ny) {
  const int row = blockIdx.x;
  const int tid = threadIdx.x;
  const float* src; unsigned short* dst; float* nd;
  if (row < NROWS) { src = x + (size_t)row * 1024; dst = xb + (size_t)row * 1024; nd = nx + row; }
  else { const int r = row - NROWS; src = y + (size_t)r * 1024; dst = yb + (size_t)r * 1024; nd = ny + r; }

  float4 v = ((const float4*)src)[tid];
  float mn = fminf(fminf(v.x, v.y), fminf(v.z, v.w));
  #pragma unroll
  for (int m = 1; m < 64; m <<= 1) mn = fminf(mn, __shfl_xor(mn, m));
  __shared__ float wred[4];
  const int w = tid >> 6, l = tid & 63;
  if (l == 0) wred[w] = mn;
  __syncthreads();
  mn = fminf(fminf(wred[0], wred[1]), fminf(wred[2], wred[3]));
  __syncthreads();   // wred reused below

  const unsigned short b0 = f2bf(v.x - mn), b1 = f2bf(v.y - mn);
  const unsigned short b2 = f2bf(v.z - mn), b3 = f2bf(v.w - mn);
  ushort4 ub; ub.x = b0; ub.y = b1; ub.z = b2; ub.w = b3;
  ((ushort4*)dst)[tid] = ub;
  const float f0 = bf2f(b0), f1 = bf2f(b1), f2 = bf2f(b2), f3 = bf2f(b3);
  float acc = f0 * f0 + f1 * f1 + f2 * f2 + f3 * f3;
  #pragma unroll
  for (int m = 1; m < 64; m <<= 1) acc += __shfl_xor(acc, m);
  if (l == 0) wred[w] = acc;
  __syncthreads();
  if (tid == 0) *nd = wred[0] + wred[1] + wred[2] + wred[3];
}

// ---------------------------------------------------------------------------
// C[i][j] = max(nx_i + ny_j - 2*dot(xb_i, yb_j), 0).  128x128 block tile,
// 4 waves as 2x2, each wave 64x64 = 4x4 MFMA 16x16x32 tiles, frags straight
// from global (L2-cached).  Also block-reduced atomicMax of C (uint trick).
__global__ __launch_bounds__(256) void cost_gemm_kernel(
    const unsigned short* __restrict__ xb, const unsigned short* __restrict__ yb,
    const float* __restrict__ nx, const float* __restrict__ ny,
    float* __restrict__ C, unsigned* __restrict__ maxCbits) {
  const int tid = threadIdx.x;
  const int w = tid >> 6, l = tid & 63;
  const int wr = w >> 1, wc = w & 1;
  const int i0 = blockIdx.y * 128 + wr * 64;
  const int j0 = blockIdx.x * 128 + wc * 64;
  const int m16 = l & 15, q = l >> 4;

  const unsigned short* ap = xb + (size_t)(i0 + m16) * 1024 + q * 8;
  const unsigned short* bp = yb + (size_t)(j0 + m16) * 1024 + q * 8;

  floatx4 acc[4][4];
  #pragma unroll
  for (int a = 0; a < 4; ++a)
    #pragma unroll
    for (int b = 0; b < 4; ++b) acc[a][b] = (floatx4){0.f, 0.f, 0.f, 0.f};

  for (int k0 = 0; k0 < 1024; k0 += 32) {
    short8 av[4], bv[4];
    #pragma unroll
    for (int t = 0; t < 4; ++t) av[t] = *(const short8*)(ap + (size_t)t * 16 * 1024 + k0);
    #pragma unroll
    for (int t = 0; t < 4; ++t) bv[t] = *(const short8*)(bp + (size_t)t * 16 * 1024 + k0);
    #pragma unroll
    for (int ti = 0; ti < 4; ++ti)
      #pragma unroll
      for (int tj = 0; tj < 4; ++tj)
        acc[ti][tj] = __builtin_amdgcn_mfma_f32_16x16x32_bf16(av[ti], bv[tj], acc[ti][tj], 0, 0, 0);
  }

  float mx = 0.f;
  #pragma unroll
  for (int ti = 0; ti < 4; ++ti) {
    #pragma unroll
    for (int tj = 0; tj < 4; ++tj) {
      const int i = i0 + ti * 16 + q * 4;       // C/D: row = quad*4+reg
      const int j = j0 + tj * 16 + m16;         //       col = lane&15
      const float nyj = ny[j];
      #pragma unroll
      for (int r = 0; r < 4; ++r) {
        float c = nx[i + r] + nyj - 2.0f * acc[ti][tj][r];
        c = fmaxf(c, 0.0f);
        C[(size_t)(i + r) * 2048 + j] = c;
        mx = fmaxf(mx, c);
      }
    }
  }
  __shared__ float mred[4];
  #pragma unroll
  for (int m = 1; m < 64; m <<= 1) mx = fmaxf(mx, __shfl_xor(mx, m));
  if (l == 0) mred[w] = mx;
  __syncthreads();
  if (tid == 0) {
    const float bm = fmaxf(fmaxf(mred[0], mred[1]), fmaxf(mred[2], mred[3]));
    atomicMax(maxCbits, __float_as_uint(bm));   // C >= 0 -> uint order == float order
  }
}

// ---------------------------------------------------------------------------
// Persistent dataflow Sinkhorn. Block b: rows [16b,16b+16) via Ks, columns
// [8b,8b+8) via KsT. Per iteration it (tag = it):
//   pass1: u_i = (a/(Ks@v))^fi          -> publish 16 tagged u's (sc0sc1)
//   poll full u[4096] by tag            -> us LDS  (implicit sync #1)
//   pass2: t_j = KsT[:,j] . u (local!)  -> v_j = (b/t_j)^fi -> publish 8
//   poll full v[2048] by tag            -> vs LDS  (implicit sync #2)
// Epilogue: flow.T[j][i] = u_i K_ij v_j + dist = sum C*flow.
__global__ __launch_bounds__(256) void sinkhorn_kernel(
    const float* __restrict__ C, const unsigned* __restrict__ maxCbits,
    unsigned long long* __restrict__ uglob, unsigned long long* __restrict__ vglob,
    float* __restrict__ out) {
  __shared__ __align__(16) unsigned short Ks[16 * 2048];   // 64 KB rows
  __shared__ __align__(16) unsigned short KsT[8 * 4096];   // 64 KB cols
  __shared__ __align__(16) float us[4096];                 // 16 KB
  __shared__ __align__(16) float vs[2048];                 // 8 KB
  __shared__ __align__(16) float uloc[16];
  __shared__ float dred[4];

  const int tid = threadIdx.x;
  const int bid = blockIdx.x;
  const int w = tid >> 6, l = tid & 63;
  const int i0 = bid * 16;
  const int jb = bid * 8;

  const float fi = 0.8333333333333334f;   // 0.5/(0.5+0.1)
  const float av = 1.0f / 4096.0f;
  const float bv = 1.0f / 2048.0f;

  // ---- prologue: Ks rows + KsT cols from C (identical exp/round both sides),
  //      v = 1/m
  {
    const float sc = -1.0f / (0.1f * __uint_as_float(*maxCbits));
    for (int il = 0; il < 16; ++il) {
      const float* cp = C + (size_t)(i0 + il) * 2048 + tid * 8;
      const float4 c0 = *(const float4*)cp;
      const float4 c1 = *(const float4*)(cp + 4);
      uint4 pk;
      pk.x = (unsigned)f2bf(__expf(c0.x * sc)) | ((unsigned)f2bf(__expf(c0.y * sc)) << 16);
      pk.y = (unsigned)f2bf(__expf(c0.z * sc)) | ((unsigned)f2bf(__expf(c0.w * sc)) << 16);
      pk.z = (unsigned)f2bf(__expf(c1.x * sc)) | ((unsigned)f2bf(__expf(c1.y * sc)) << 16);
      pk.w = (unsigned)f2bf(__expf(c1.z * sc)) | ((unsigned)f2bf(__expf(c1.w * sc)) << 16);
      *(uint4*)&Ks[il * 2048 + tid * 8] = pk;
    }
    // KsT: column slice C[:, jb..jb+8), strided gather (one-time cost)
    #pragma unroll
    for (int k = 0; k < 16; ++k) {
      const int i = tid + (k << 8);
      const float* cp = C + (size_t)i * 2048 + jb;
      const float4 c0 = *(const float4*)cp;
      const float4 c1 = *(const float4*)(cp + 4);
      KsT[0 * 4096 + i] = f2bf(__expf(c0.x * sc));
      KsT[1 * 4096 + i] = f2bf(__expf(c0.y * sc));
      KsT[2 * 4096 + i] = f2bf(__expf(c0.z * sc));
      KsT[3 * 4096 + i] = f2bf(__expf(c0.w * sc));
      KsT[4 * 4096 + i] = f2bf(__expf(c1.x * sc));
      KsT[5 * 4096 + i] = f2bf(__expf(c1.y * sc));
      KsT[6 * 4096 + i] = f2bf(__expf(c1.z * sc));
      KsT[7 * 4096 + i] = f2bf(__expf(c1.w * sc));
    }
    const float4 vinit = make_float4(bv, bv, bv, bv);
    *(float4*)&vs[tid * 8] = vinit;
    *(float4*)&vs[tid * 8 + 4] = vinit;
  }
  __syncthreads();

  for (int it = 1; it <= NITER; ++it) {
    const unsigned tagit = (unsigned)it;

    // ---- pass 1: wave w rows w*4..w*4+3; u = (a/(K v))^fi; publish tagged
    float part[4] = {0.f, 0.f, 0.f, 0.f};
    const int r0 = w * 4;
    #pragma unroll
    for (int c = 0; c < 4; ++c) {
      const int j0 = c * 512 + l * 8;
      const float4 va = *(const float4*)&vs[j0];
      const float4 vb = *(const float4*)&vs[j0 + 4];
      #pragma unroll
      for (int rr = 0; rr < 4; ++rr) {
        const uint4 kb = *(const uint4*)&Ks[(r0 + rr) * 2048 + j0];
        part[rr] += bf2f((unsigned short)kb.x) * va.x + bf2f((unsigned short)(kb.x >> 16)) * va.y
                 +  bf2f((unsigned short)kb.y) * va.z + bf2f((unsigned short)(kb.y >> 16)) * va.w
                 +  bf2f((unsigned short)kb.z) * vb.x + bf2f((unsigned short)(kb.z >> 16)) * vb.y
                 +  bf2f((unsigned short)kb.w) * vb.z + bf2f((unsigned short)(kb.w >> 16)) * vb.w;
      }
    }
    #pragma unroll
    for (int m = 1; m < 64; m <<= 1) {
      part[0] += __shfl_xor(part[0], m);
      part[1] += __shfl_xor(part[1], m);
      part[2] += __shfl_xor(part[2], m);
      part[3] += __shfl_xor(part[3], m);
    }
    if (l == 0) {
      #pragma unroll
      for (int r = 0; r < 4; ++r) {
        const float uv = powfi(av / part[r], fi);
        uloc[r0 + r] = uv;
        __hip_atomic_store(&uglob[i0 + r0 + r], packvt(uv, tagit),
                           __ATOMIC_RELAXED, __HIP_MEMORY_SCOPE_AGENT);
      }
    }

    // ---- poll full u (entries tid+256k), tag==it -> us  (implicit sync #1)
    {
      unsigned pend = 0xFFFFu;
      do {
        unsigned long long g[16];
        #pragma unroll
        for (int k = 0; k < 16; ++k)
          if (pend & (1u << k))
            g[k] = __hip_atomic_load(&uglob[tid + (k << 8)],
                                     __ATOMIC_RELAXED, __HIP_MEMORY_SCOPE_AGENT);
        #pragma unroll
        for (int k = 0; k < 16; ++k)
          if (pend & (1u << k)) {
            if ((unsigned)(g[k] >> 32) == tagit) {
              us[tid + (k << 8)] = __uint_as_float((unsigned)g[k]);
              pend &= ~(1u << k);
            }
          }
        if (pend) __builtin_amdgcn_s_sleep(1);
      } while (pend);
    }
    __syncthreads();

    // ---- pass 2: wave w owns cols jb+2w, jb+2w+1; t_j local via KsT
    {
      float t0 = 0.f, t1 = 0.f;
      const int ca = (2 * w) * 4096;
      const int cb = (2 * w + 1) * 4096;
      #pragma unroll
      for (int c = 0; c < 8; ++c) {
        const int ic = c * 512 + l * 8;
        const float4 ua = *(const float4*)&us[ic];
        const float4 ub = *(const float4*)&us[ic + 4];
        const uint4 ka = *(const uint4*)&KsT[ca + ic];
        const uint4 kb = *(const uint4*)&KsT[cb + ic];
        t0 += bf2f((unsigned short)ka.x) * ua.x + bf2f((unsigned short)(ka.x >> 16)) * ua.y
           +  bf2f((unsigned short)ka.y) * ua.z + bf2f((unsigned short)(ka.y >> 16)) * ua.w
           +  bf2f((unsigned short)ka.z) * ub.x + bf2f((unsigned short)(ka.z >> 16)) * ub.y
           +  bf2f((unsigned short)ka.w) * ub.z + bf2f((unsigned short)(ka.w >> 16)) * ub.w;
        t1 += bf2f((unsigned short)kb.x) * ua.x + bf2f((unsigned short)(kb.x >> 16)) * ua.y
           +  bf2f((unsigned short)kb.y) * ua.z + bf2f((unsigned short)(kb.y >> 16)) * ua.w
           +  bf2f((unsigned short)kb.z) * ub.x + bf2f((unsigned short)(kb.z >> 16)) * ub.y
           +  bf2f((unsigned short)kb.w) * ub.z + bf2f((unsigned short)(kb.w >> 16)) * ub.w;
      }
      #pragma unroll
      for (int m = 1; m < 64; m <<= 1) {
        t0 += __shfl_xor(t0, m);
        t1 += __shfl_xor(t1, m);
      }
      if (l == 0) {
        __hip_atomic_store(&vglob[jb + 2 * w], packvt(powfi(bv / t0, fi), tagit),
                           __ATOMIC_RELAXED, __HIP_MEMORY_SCOPE_AGENT);
        __hip_atomic_store(&vglob[jb + 2 * w + 1], packvt(powfi(bv / t1, fi), tagit),
                           __ATOMIC_RELAXED, __HIP_MEMORY_SCOPE_AGENT);
      }
    }

    // ---- poll full v (entries tid+256k, k<8) -> vs  (implicit sync #2)
    {
      unsigned pend = 0xFFu;
      do {
        unsigned long long g[8];
        #pragma unroll
        for (int k = 0; k < 8; ++k)
          if (pend & (1u << k))
            g[k] = __hip_atomic_load(&vglob[tid + (k << 8)],
                                     __ATOMIC_RELAXED, __HIP_MEMORY_SCOPE_AGENT);
        #pragma unroll
        for (int k = 0; k < 8; ++k)
          if (pend & (1u << k)) {
            if ((unsigned)(g[k] >> 32) == tagit) {
              vs[tid + (k << 8)] = __uint_as_float((unsigned)g[k]);
              pend &= ~(1u << k);
            }
          }
        if (pend) __builtin_amdgcn_s_sleep(1);
      } while (pend);
    }
    __syncthreads();
  }

  // ---- epilogue: flow.T[j][i0..i0+15] (64B contiguous stores) + dist
  float ur[16];
  *(float4*)&ur[0]  = *(const float4*)&uloc[0];
  *(float4*)&ur[4]  = *(const float4*)&uloc[4];
  *(float4*)&ur[8]  = *(const float4*)&uloc[8];
  *(float4*)&ur[12] = *(const float4*)&uloc[12];
  float distp = 0.f;
  for (int sub = 0; sub < 8; ++sub) {
    const int j = w * 512 + sub * 64 + l;
    const float vj = vs[j];
    float o[16];
    #pragma unroll
    for (int il = 0; il < 16; ++il) {
      const float kf = bf2f(Ks[il * 2048 + j]);
      const float fl = ur[il] * kf * vj;
      o[il] = fl;
      distp += C[(size_t)(i0 + il) * 2048 + j] * fl;
    }
    float* op = out + (size_t)j * 4096 + i0;
    *(float4*)(op)      = make_float4(o[0],  o[1],  o[2],  o[3]);
    *(float4*)(op + 4)  = make_float4(o[4],  o[5],  o[6],  o[7]);
    *(float4*)(op + 8)  = make_float4(o[8],  o[9],  o[10], o[11]);
    *(float4*)(op + 12) = make_float4(o[12], o[13], o[14], o[15]);
  }
  #pragma unroll
  for (int m = 1; m < 64; m <<= 1) distp += __shfl_xor(distp, m);
  if (l == 0) dred[w] = distp;
  __syncthreads();
  if (tid == 0) unsafeAtomicAdd(out + (size_t)8388608, dred[0] + dred[1] + dred[2] + dred[3]);
}

// ---------------------------------------------------------------------------
extern "C" void kernel_launch(void* const* d_in, const int* in_sizes, int n_in,
                              void* d_out, int out_size, void* d_ws, size_t ws_size,
                              hipStream_t stream) {
  (void)in_sizes; (void)n_in; (void)out_size; (void)ws_size;
  const float* x = (const float*)d_in[0];
  const float* y = (const float*)d_in[1];
  float* out = (float*)d_out;
  char* ws = (char*)d_ws;

  // workspace layout (bytes)
  float*              Cmat  = (float*)(ws + 0);                 // 32 MB
  unsigned short*     xb    = (unsigned short*)(ws + 33554432); // 8 MB
  unsigned short*     yb    = (unsigned short*)(ws + 41943040); // 4 MB
  float*              nx    = (float*)(ws + 46137344);          // 16 KB
  float*              ny    = (float*)(ws + 46153728);          // 8 KB
  unsigned*           maxC  = (unsigned*)(ws + 46161920);
  unsigned long long* uglob = (unsigned long long*)(ws + 46162432); // 32 KB tagged
  unsigned long long* vglob = (unsigned long long*)(ws + 46195200); // 16 KB tagged

  hipLaunchKernelGGL(zero_kernel, dim3(1), dim3(64), 0, stream, maxC, out);
  hipLaunchKernelGGL(prep_kernel, dim3(6144), dim3(256), 0, stream, x, y, xb, yb, nx, ny);
  hipLaunchKernelGGL(cost_gemm_kernel, dim3(16, 32), dim3(256), 0, stream, xb, yb, nx, ny, Cmat, maxC);
  hipLaunchKernelGGL(sinkhorn_kernel, dim3(NBLK), dim3(256), 0, stream,
                     Cmat, maxC, uglob, vglob, out);
}

// Round 5
// 955.467 us; speedup vs baseline: 3.7227x; 1.3501x over previous
//
#include <hip/hip_runtime.h>

// ---------------------------------------------------------------------------
// OT_Attn: unbalanced Sinkhorn on MI355X.
// R5: flag-throttled burst exchange. R3's 4.9 us/exchange was 65K threads
// retry-polling per-entry tags against not-yet-published data (fabric fan-in).
// Now: per-block done flags -> single aggregator block -> root flag -> tid0
// spin -> one-round burst read (per-entry tag-verify kept as a correctness
// backstop; worst case degrades to R3, never wrong). ONLY validated relaxed
// AGENT __hip_atomic ops touch shared sync state -- no inline asm, no plain
// load spins (R4's hang: plain uniform-address spin can scalarize to the
// scalar K$, which buffer_inv does not invalidate).
// ---------------------------------------------------------------------------

#define NROWS 4096
#define MCOLS 2048
#define NITER 100
#define NBLK  256   // 1 block/CU (LDS-bound), grid == CU count -> co-resident

using short8  = __attribute__((ext_vector_type(8))) short;
using floatx4 = __attribute__((ext_vector_type(4))) float;

__device__ __forceinline__ float bf2f(unsigned short u) {
  return __uint_as_float(((unsigned)u) << 16);
}
__device__ __forceinline__ unsigned short f2bf(float f) {  // RNE
  unsigned u = __float_as_uint(f);
  u += 0x7fffu + ((u >> 16) & 1u);
  return (unsigned short)(u >> 16);
}
__device__ __forceinline__ float powfi(float x, float fi) {
  return __expf(fi * __logf(x));
}
__device__ __forceinline__ unsigned long long packvt(float v, unsigned tag) {
  return ((unsigned long long)tag << 32) | (unsigned long long)__float_as_uint(v);
}
__device__ __forceinline__ unsigned aload(const unsigned* p) {
  return __hip_atomic_load(p, __ATOMIC_RELAXED, __HIP_MEMORY_SCOPE_AGENT);
}
__device__ __forceinline__ void astore(unsigned* p, unsigned v) {
  __hip_atomic_store(p, v, __ATOMIC_RELAXED, __HIP_MEMORY_SCOPE_AGENT);
}

// ---------------------------------------------------------------------------
__global__ void zero_kernel(unsigned* maxCbits, float* out) {
  if (threadIdx.x == 0) { *maxCbits = 0u; out[8388608] = 0.0f; }
}

// ---------------------------------------------------------------------------
// One block per row (4096 x-rows then 2048 y-rows): min-shift, bf16 round,
// squared norm OF THE ROUNDED VALUES (consistent with the bf16 GEMM).
__global__ __launch_bounds__(256) void prep_kernel(
    const float* __restrict__ x, const float* __restrict__ y,
    unsigned short* __restrict__ xb, unsigned short* __restrict__ yb,
    float* __restrict__ nx, float* __restrict__ ny) {
  const int row = blockIdx.x;
  const int tid = threadIdx.x;
  const float* src; unsigned short* dst; float* nd;
  if (row < NROWS) { src = x + (size_t)row * 1024; dst = xb + (size_t)row * 1024; nd = nx + row; }
  else { const int r = row - NROWS; src = y + (size_t)r * 1024; dst = yb + (size_t)r * 1024; nd = ny + r; }

  float4 v = ((const float4*)src)[tid];
  float mn = fminf(fminf(v.x, v.y), fminf(v.z, v.w));
  #pragma unroll
  for (int m = 1; m < 64; m <<= 1) mn = fminf(mn, __shfl_xor(mn, m));
  __shared__ float wred[4];
  const int w = tid >> 6, l = tid & 63;
  if (l == 0) wred[w] = mn;
  __syncthreads();
  mn = fminf(fminf(wred[0], wred[1]), fminf(wred[2], wred[3]));
  __syncthreads();   // wred reused below

  const unsigned short b0 = f2bf(v.x - mn), b1 = f2bf(v.y - mn);
  const unsigned short b2 = f2bf(v.z - mn), b3 = f2bf(v.w - mn);
  ushort4 ub; ub.x = b0; ub.y = b1; ub.z = b2; ub.w = b3;
  ((ushort4*)dst)[tid] = ub;
  const float f0 = bf2f(b0), f1 = bf2f(b1), f2 = bf2f(b2), f3 = bf2f(b3);
  float acc = f0 * f0 + f1 * f1 + f2 * f2 + f3 * f3;
  #pragma unroll
  for (int m = 1; m < 64; m <<= 1) acc += __shfl_xor(acc, m);
  if (l == 0) wred[w] = acc;
  __syncthreads();
  if (tid == 0) *nd = wred[0] + wred[1] + wred[2] + wred[3];
}

// ---------------------------------------------------------------------------
// C[i][j] = max(nx_i + ny_j - 2*dot(xb_i, yb_j), 0).  128x128 block tile,
// 4 waves as 2x2, each wave 64x64 = 4x4 MFMA 16x16x32 tiles.
__global__ __launch_bounds__(256) void cost_gemm_kernel(
    const unsigned short* __restrict__ xb, const unsigned short* __restrict__ yb,
    const float* __restrict__ nx, const float* __restrict__ ny,
    float* __restrict__ C, unsigned* __restrict__ maxCbits) {
  const int tid = threadIdx.x;
  const int w = tid >> 6, l = tid & 63;
  const int wr = w >> 1, wc = w & 1;
  const int i0 = blockIdx.y * 128 + wr * 64;
  const int j0 = blockIdx.x * 128 + wc * 64;
  const int m16 = l & 15, q = l >> 4;

  const unsigned short* ap = xb + (size_t)(i0 + m16) * 1024 + q * 8;
  const unsigned short* bp = yb + (size_t)(j0 + m16) * 1024 + q * 8;

  floatx4 acc[4][4];
  #pragma unroll
  for (int a = 0; a < 4; ++a)
    #pragma unroll
    for (int b = 0; b < 4; ++b) acc[a][b] = (floatx4){0.f, 0.f, 0.f, 0.f};

  for (int k0 = 0; k0 < 1024; k0 += 32) {
    short8 av[4], bv[4];
    #pragma unroll
    for (int t = 0; t < 4; ++t) av[t] = *(const short8*)(ap + (size_t)t * 16 * 1024 + k0);
    #pragma unroll
    for (int t = 0; t < 4; ++t) bv[t] = *(const short8*)(bp + (size_t)t * 16 * 1024 + k0);
    #pragma unroll
    for (int ti = 0; ti < 4; ++ti)
      #pragma unroll
      for (int tj = 0; tj < 4; ++tj)
        acc[ti][tj] = __builtin_amdgcn_mfma_f32_16x16x32_bf16(av[ti], bv[tj], acc[ti][tj], 0, 0, 0);
  }

  float mx = 0.f;
  #pragma unroll
  for (int ti = 0; ti < 4; ++ti) {
    #pragma unroll
    for (int tj = 0; tj < 4; ++tj) {
      const int i = i0 + ti * 16 + q * 4;       // C/D: row = quad*4+reg
      const int j = j0 + tj * 16 + m16;         //       col = lane&15
      const float nyj = ny[j];
      #pragma unroll
      for (int r = 0; r < 4; ++r) {
        float c = nx[i + r] + nyj - 2.0f * acc[ti][tj][r];
        c = fmaxf(c, 0.0f);
        C[(size_t)(i + r) * 2048 + j] = c;
        mx = fmaxf(mx, c);
      }
    }
  }
  __shared__ float mred[4];
  #pragma unroll
  for (int m = 1; m < 64; m <<= 1) mx = fmaxf(mx, __shfl_xor(mx, m));
  if (l == 0) mred[w] = mx;
  __syncthreads();
  if (tid == 0) {
    const float bm = fmaxf(fmaxf(mred[0], mred[1]), fmaxf(mred[2], mred[3]));
    atomicMax(maxCbits, __float_as_uint(bm));
  }
}

// ---------------------------------------------------------------------------
// Persistent dataflow Sinkhorn. Block b: rows [16b,16b+16) via Ks, columns
// [8b,8b+8) via KsT. Per iteration it (tag = it):
//   pass1 -> publish 16 tagged u's -> blkflag -> agg(bid0) -> uroot ->
//   tid0 spin -> burst read u (tag-verified) -> us LDS
//   pass2 -> publish 8 tagged v's -> blkflag -> agg(bid1) -> vroot ->
//   tid0 spin -> burst read v -> vs LDS
__global__ __launch_bounds__(256) void sinkhorn_kernel(
    const float* __restrict__ C, const unsigned* __restrict__ maxCbits,
    unsigned long long* __restrict__ uglob, unsigned long long* __restrict__ vglob,
    unsigned* __restrict__ ublkflag, unsigned* __restrict__ vblkflag,
    unsigned* __restrict__ uroot, unsigned* __restrict__ vroot,
    float* __restrict__ out) {
  __shared__ __align__(16) unsigned short Ks[16 * 2048];   // 64 KB rows
  __shared__ __align__(16) unsigned short KsT[8 * 4096];   // 64 KB cols
  __shared__ __align__(16) float us[4096];                 // 16 KB
  __shared__ __align__(16) float vs[2048];                 // 8 KB
  __shared__ __align__(16) float uloc[16];
  __shared__ float dred[4];

  const int tid = threadIdx.x;
  const int bid = blockIdx.x;
  const int w = tid >> 6, l = tid & 63;
  const int i0 = bid * 16;
  const int jb = bid * 8;

  const float fi = 0.8333333333333334f;   // 0.5/(0.5+0.1)
  const float av = 1.0f / 4096.0f;
  const float bv = 1.0f / 2048.0f;

  // ---- prologue: Ks rows + KsT cols from C (identical exp/round both sides),
  //      v = 1/m
  {
    const float sc = -1.0f / (0.1f * __uint_as_float(*maxCbits));
    for (int il = 0; il < 16; ++il) {
      const float* cp = C + (size_t)(i0 + il) * 2048 + tid * 8;
      const float4 c0 = *(const float4*)cp;
      const float4 c1 = *(const float4*)(cp + 4);
      uint4 pk;
      pk.x = (unsigned)f2bf(__expf(c0.x * sc)) | ((unsigned)f2bf(__expf(c0.y * sc)) << 16);
      pk.y = (unsigned)f2bf(__expf(c0.z * sc)) | ((unsigned)f2bf(__expf(c0.w * sc)) << 16);
      pk.z = (unsigned)f2bf(__expf(c1.x * sc)) | ((unsigned)f2bf(__expf(c1.y * sc)) << 16);
      pk.w = (unsigned)f2bf(__expf(c1.z * sc)) | ((unsigned)f2bf(__expf(c1.w * sc)) << 16);
      *(uint4*)&Ks[il * 2048 + tid * 8] = pk;
    }
    // KsT: column slice C[:, jb..jb+8), strided gather (one-time cost)
    #pragma unroll
    for (int k = 0; k < 16; ++k) {
      const int i = tid + (k << 8);
      const float* cp = C + (size_t)i * 2048 + jb;
      const float4 c0 = *(const float4*)cp;
      const float4 c1 = *(const float4*)(cp + 4);
      KsT[0 * 4096 + i] = f2bf(__expf(c0.x * sc));
      KsT[1 * 4096 + i] = f2bf(__expf(c0.y * sc));
      KsT[2 * 4096 + i] = f2bf(__expf(c0.z * sc));
      KsT[3 * 4096 + i] = f2bf(__expf(c0.w * sc));
      KsT[4 * 4096 + i] = f2bf(__expf(c1.x * sc));
      KsT[5 * 4096 + i] = f2bf(__expf(c1.y * sc));
      KsT[6 * 4096 + i] = f2bf(__expf(c1.z * sc));
      KsT[7 * 4096 + i] = f2bf(__expf(c1.w * sc));
    }
    const float4 vinit = make_float4(bv, bv, bv, bv);
    *(float4*)&vs[tid * 8] = vinit;
    *(float4*)&vs[tid * 8 + 4] = vinit;
  }
  __syncthreads();

  for (int it = 1; it <= NITER; ++it) {
    const unsigned tagit = (unsigned)it;

    // ---- pass 1: wave w rows w*4..w*4+3; u = (a/(K v))^fi; publish tagged
    float part[4] = {0.f, 0.f, 0.f, 0.f};
    const int r0 = w * 4;
    #pragma unroll
    for (int c = 0; c < 4; ++c) {
      const int j0 = c * 512 + l * 8;
      const float4 va = *(const float4*)&vs[j0];
      const float4 vb = *(const float4*)&vs[j0 + 4];
      #pragma unroll
      for (int rr = 0; rr < 4; ++rr) {
        const uint4 kb = *(const uint4*)&Ks[(r0 + rr) * 2048 + j0];
        part[rr] += bf2f((unsigned short)kb.x) * va.x + bf2f((unsigned short)(kb.x >> 16)) * va.y
                 +  bf2f((unsigned short)kb.y) * va.z + bf2f((unsigned short)(kb.y >> 16)) * va.w
                 +  bf2f((unsigned short)kb.z) * vb.x + bf2f((unsigned short)(kb.z >> 16)) * vb.y
                 +  bf2f((unsigned short)kb.w) * vb.z + bf2f((unsigned short)(kb.w >> 16)) * vb.w;
      }
    }
    #pragma unroll
    for (int m = 1; m < 64; m <<= 1) {
      part[0] += __shfl_xor(part[0], m);
      part[1] += __shfl_xor(part[1], m);
      part[2] += __shfl_xor(part[2], m);
      part[3] += __shfl_xor(part[3], m);
    }
    if (l == 0) {
      #pragma unroll
      for (int r = 0; r < 4; ++r) {
        const float uv = powfi(av / part[r], fi);
        uloc[r0 + r] = uv;
        __hip_atomic_store(&uglob[i0 + r0 + r], packvt(uv, tagit),
                           __ATOMIC_RELAXED, __HIP_MEMORY_SCOPE_AGENT);
      }
    }
    __syncthreads();   // drains all waves' stores (vmcnt 0) before flagging
    if (tid == 0) astore(&ublkflag[bid], tagit);

    // ---- u release: aggregator bid 0 gathers 256 flags -> uroot
    if (bid == 0) {
      while (aload(&ublkflag[tid]) != tagit) __builtin_amdgcn_s_sleep(1);
      __syncthreads();          // all flags seen
      if (tid == 0) astore(uroot, tagit);
    } else {
      if (tid == 0)
        while (aload(uroot) != tagit) __builtin_amdgcn_s_sleep(1);
      __syncthreads();          // block released
    }

    // ---- burst read u (one round expected; tag-verify as backstop)
    {
      unsigned pend = 0xFFFFu;
      do {
        unsigned long long g[16];
        #pragma unroll
        for (int k = 0; k < 16; ++k)
          if (pend & (1u << k))
            g[k] = __hip_atomic_load(&uglob[tid + (k << 8)],
                                     __ATOMIC_RELAXED, __HIP_MEMORY_SCOPE_AGENT);
        #pragma unroll
        for (int k = 0; k < 16; ++k)
          if ((pend & (1u << k)) && (unsigned)(g[k] >> 32) == tagit) {
            us[tid + (k << 8)] = __uint_as_float((unsigned)g[k]);
            pend &= ~(1u << k);
          }
        if (pend) __builtin_amdgcn_s_sleep(1);
      } while (pend);
    }
    __syncthreads();

    // ---- pass 2: wave w owns cols jb+2w, jb+2w+1; t_j local via KsT
    {
      float t0 = 0.f, t1 = 0.f;
      const int ca = (2 * w) * 4096;
      const int cb = (2 * w + 1) * 4096;
      #pragma unroll
      for (int c = 0; c < 8; ++c) {
        const int ic = c * 512 + l * 8;
        const float4 ua = *(const float4*)&us[ic];
        const float4 ub = *(const float4*)&us[ic + 4];
        const uint4 ka = *(const uint4*)&KsT[ca + ic];
        const uint4 kb = *(const uint4*)&KsT[cb + ic];
        t0 += bf2f((unsigned short)ka.x) * ua.x + bf2f((unsigned short)(ka.x >> 16)) * ua.y
           +  bf2f((unsigned short)ka.y) * ua.z + bf2f((unsigned short)(ka.y >> 16)) * ua.w
           +  bf2f((unsigned short)ka.z) * ub.x + bf2f((unsigned short)(ka.z >> 16)) * ub.y
           +  bf2f((unsigned short)ka.w) * ub.z + bf2f((unsigned short)(ka.w >> 16)) * ub.w;
        t1 += bf2f((unsigned short)kb.x) * ua.x + bf2f((unsigned short)(kb.x >> 16)) * ua.y
           +  bf2f((unsigned short)kb.y) * ua.z + bf2f((unsigned short)(kb.y >> 16)) * ua.w
           +  bf2f((unsigned short)kb.z) * ub.x + bf2f((unsigned short)(kb.z >> 16)) * ub.y
           +  bf2f((unsigned short)kb.w) * ub.z + bf2f((unsigned short)(kb.w >> 16)) * ub.w;
      }
      #pragma unroll
      for (int m = 1; m < 64; m <<= 1) {
        t0 += __shfl_xor(t0, m);
        t1 += __shfl_xor(t1, m);
      }
      if (l == 0) {
        __hip_atomic_store(&vglob[jb + 2 * w], packvt(powfi(bv / t0, fi), tagit),
                           __ATOMIC_RELAXED, __HIP_MEMORY_SCOPE_AGENT);
        __hip_atomic_store(&vglob[jb + 2 * w + 1], packvt(powfi(bv / t1, fi), tagit),
                           __ATOMIC_RELAXED, __HIP_MEMORY_SCOPE_AGENT);
      }
    }
    __syncthreads();   // drains stores
    if (tid == 0) astore(&vblkflag[bid], tagit);

    // ---- v release: aggregator bid 1 gathers 256 flags -> vroot
    if (bid == 1) {
      while (aload(&vblkflag[tid]) != tagit) __builtin_amdgcn_s_sleep(1);
      __syncthreads();
      if (tid == 0) astore(vroot, tagit);
    } else {
      if (tid == 0)
        while (aload(vroot) != tagit) __builtin_amdgcn_s_sleep(1);
      __syncthreads();
    }

    // ---- burst read v
    {
      unsigned pend = 0xFFu;
      do {
        unsigned long long g[8];
        #pragma unroll
        for (int k = 0; k < 8; ++k)
          if (pend & (1u << k))
            g[k] = __hip_atomic_load(&vglob[tid + (k << 8)],
                                     __ATOMIC_RELAXED, __HIP_MEMORY_SCOPE_AGENT);
        #pragma unroll
        for (int k = 0; k < 8; ++k)
          if ((pend & (1u << k)) && (unsigned)(g[k] >> 32) == tagit) {
            vs[tid + (k << 8)] = __uint_as_float((unsigned)g[k]);
            pend &= ~(1u << k);
          }
        if (pend) __builtin_amdgcn_s_sleep(1);
      } while (pend);
    }
    __syncthreads();
  }

  // ---- epilogue: flow.T[j][i0..i0+15] (64B contiguous stores) + dist
  float ur[16];
  *(float4*)&ur[0]  = *(const float4*)&uloc[0];
  *(float4*)&ur[4]  = *(const float4*)&uloc[4];
  *(float4*)&ur[8]  = *(const float4*)&uloc[8];
  *(float4*)&ur[12] = *(const float4*)&uloc[12];
  float distp = 0.f;
  for (int sub = 0; sub < 8; ++sub) {
    const int j = w * 512 + sub * 64 + l;
    const float vj = vs[j];
    float o[16];
    #pragma unroll
    for (int il = 0; il < 16; ++il) {
      const float kf = bf2f(Ks[il * 2048 + j]);
      const float fl = ur[il] * kf * vj;
      o[il] = fl;
      distp += C[(size_t)(i0 + il) * 2048 + j] * fl;
    }
    float* op = out + (size_t)j * 4096 + i0;
    *(float4*)(op)      = make_float4(o[0],  o[1],  o[2],  o[3]);
    *(float4*)(op + 4)  = make_float4(o[4],  o[5],  o[6],  o[7]);
    *(float4*)(op + 8)  = make_float4(o[8],  o[9],  o[10], o[11]);
    *(float4*)(op + 12) = make_float4(o[12], o[13], o[14], o[15]);
  }
  #pragma unroll
  for (int m = 1; m < 64; m <<= 1) distp += __shfl_xor(distp, m);
  if (l == 0) dred[w] = distp;
  __syncthreads();
  if (tid == 0) unsafeAtomicAdd(out + (size_t)8388608, dred[0] + dred[1] + dred[2] + dred[3]);
}

// ---------------------------------------------------------------------------
extern "C" void kernel_launch(void* const* d_in, const int* in_sizes, int n_in,
                              void* d_out, int out_size, void* d_ws, size_t ws_size,
                              hipStream_t stream) {
  (void)in_sizes; (void)n_in; (void)out_size; (void)ws_size;
  const float* x = (const float*)d_in[0];
  const float* y = (const float*)d_in[1];
  float* out = (float*)d_out;
  char* ws = (char*)d_ws;

  // workspace layout (bytes)
  float*              Cmat     = (float*)(ws + 0);                 // 32 MB
  unsigned short*     xb       = (unsigned short*)(ws + 33554432); // 8 MB
  unsigned short*     yb       = (unsigned short*)(ws + 41943040); // 4 MB
  float*              nx       = (float*)(ws + 46137344);          // 16 KB
  float*              ny       = (float*)(ws + 46153728);          // 8 KB
  unsigned*           maxC     = (unsigned*)(ws + 46161920);
  unsigned long long* uglob    = (unsigned long long*)(ws + 46162432); // 32 KB
  unsigned long long* vglob    = (unsigned long long*)(ws + 46195200); // 16 KB
  unsigned*           ublkflag = (unsigned*)(ws + 46211584);       // 256 u32
  unsigned*           vblkflag = (unsigned*)(ws + 46212608);       // 256 u32
  unsigned*           uroot    = (unsigned*)(ws + 46213632);
  unsigned*           vroot    = (unsigned*)(ws + 46213760);

  hipLaunchKernelGGL(zero_kernel, dim3(1), dim3(64), 0, stream, maxC, out);
  hipLaunchKernelGGL(prep_kernel, dim3(6144), dim3(256), 0, stream, x, y, xb, yb, nx, ny);
  hipLaunchKernelGGL(cost_gemm_kernel, dim3(16, 32), dim3(256), 0, stream, xb, yb, nx, ny, Cmat, maxC);
  hipLaunchKernelGGL(sinkhorn_kernel, dim3(NBLK), dim3(256), 0, stream,
                     Cmat, maxC, uglob, vglob, ublkflag, vblkflag, uroot, vroot, out);
}